// Round 8
// baseline (733.623 us; speedup 1.0000x reference)
//
#include <hip/hip_runtime.h>

// ---------------- common helpers ----------------

typedef __attribute__((ext_vector_type(8))) short s16x8;   // 8 x bf16 (4 VGPRs)
typedef __attribute__((ext_vector_type(4))) float f32x4;   // 16x16 MFMA accumulator

__device__ __forceinline__ unsigned short f2bf(float f) {
  union { float f; unsigned u; } v; v.f = f;
  unsigned r = v.u + 0x7fffu + ((v.u >> 16) & 1u);   // round-to-nearest-even
  return (unsigned short)(r >> 16);
}
__device__ __forceinline__ float bf2f(unsigned short h) {
  union { unsigned u; float f; } v; v.u = ((unsigned)h) << 16; return v.f;
}
__device__ __forceinline__ void gload_lds16(const void* g, void* l) {
  __builtin_amdgcn_global_load_lds(
      (const __attribute__((address_space(1))) void*)g,
      (__attribute__((address_space(3))) void*)l, 16, 0, 0);
}

// ---------------- fp32 -> bf16 convert: ALL 4 weights, one dispatch ----------

__global__ void conv_bf16_4(const float4* __restrict__ w0,
                            const float4* __restrict__ w1,
                            const float4* __restrict__ w2,
                            const float4* __restrict__ w3,
                            ushort4* __restrict__ dst, int n4) {
  int i = blockIdx.x * blockDim.x + threadIdx.x;
  if (i >= n4) return;
  int w = blockIdx.y;
  const float4* src = (w == 0) ? w0 : (w == 1) ? w1 : (w == 2) ? w2 : w3;
  float4 v = src[i];
  ushort4 o;
  o.x = f2bf(v.x); o.y = f2bf(v.y); o.z = f2bf(v.z); o.w = f2bf(v.w);
  dst[(long long)w * n4 + i] = o;
}

// ---- fused mix+GEMM: C[y] = mix_y(hidden) @ W_y^T for y in {k,v,r} --------
// 256x256 tile, BK=32, 8 waves (2M x 4N, per-wave 128x64 of 16x16x32 frags —
// r5-verified frag/C-D mappings). ONE dispatch, grid (256, 3): y selects
// {tm vector, weight, output, epilogue}. A is built ON THE FLY: load hidden
// fp32 (cur row + prev row, prev zeroed at s==0 via psel), mix with tm
// (preloaded to LDS once), cvt to bf16, swizzled ds_write_b128. B staged via
// global_load_lds (r5's zero-conflict inverse-swizzle pair).
// LDS: A ring-2 (2 x 16 KiB) + B ring-3 (3 x 16 KiB) + tm (8 KiB) = 88 KiB.
// vmcnt LEDGER (per-thread issue order, all VMEM ops compiler-visible):
//   P0(t): H(t+2) 8 loads ; P1(t): C(t+2) 2 gload_lds.
//   Queue entering P0(t): [H(t+1) 8, C(t+1) 2].
//   P0(t): issue H(t+2) -> retire-through H(t+1): younger = C(t+1)2 +
//          H(t+2)8 = vmcnt(10). H consumed by the SAME wave (reg loads) so
//          no barrier needed for H. DO_MIX(t+1) then safe.
//   P1(t): issue C(t+2) -> retire-through C(t+1): younger = H(t+2)8 +
//          C(t+2)2 = vmcnt(10), placed BEFORE P1's barrier => every wave's
//          C(t+1) landed before any wave passes that barrier => P0(t+1)'s
//          b-reads are race-free (cross-wave visibility rule).
//   Tails: P0: t+2==NT -> vmcnt(2) (retire H(t+1); younger=C(t+1)2);
//          P1: t+2==NT -> vmcnt(0) (retire C(t+1)); last iter: none.
// WAR: A slot (t+1)&1 re-written at P0(t) — its previous tenant (tile t-1)
//   was fully read by P1(t-1) (lgkmcnt(0) before its trailing barrier).
//   B slot (t+2)%3 = (t-1)%3 re-written at P1(t) — tile t-1's B-reads
//   drained at P0(t-1)'s lgkmcnt(0), before barriers preceding P1(t).
// ds_write visibility: W(t+1) writes drain at P0(t)'s lgkmcnt(0); readers
//   touch them at P0(t+1), after P0(t)'s trailing barrier. Safe.
// tm preload: one float4/thread, fully drained (vmcnt0+lgkm0+sched_barrier)
//   before the pipeline starts so the manual ledger stays exact.

__global__ __launch_bounds__(512, 2) void gemm_kvr(
    const float* __restrict__ hidden,
    const unsigned short* __restrict__ Wb,   // 3 contiguous [H,H] bf16
    const float* __restrict__ tmk, const float* __restrict__ tmv,
    const float* __restrict__ tmr,
    unsigned short* __restrict__ Ck, unsigned short* __restrict__ Cv,
    unsigned short* __restrict__ Cr,
    int M, int N, int K, int S) {
  // shorts: A 2*8192 | B 3*8192 | tm 2048 floats (4096 shorts) = 88 KiB
  __shared__ unsigned short lds[2 * 8192 + 3 * 8192 + 4096];
  float* ltm = (float*)(lds + 40960);

  const int tid = threadIdx.x;
  const int wave = tid >> 6;
  const int lane = tid & 63;
  const int y = (int)blockIdx.y;

  const unsigned short* B = Wb + (long long)y * N * K;
  const float* tm = (y == 0) ? tmk : (y == 1) ? tmv : tmr;
  unsigned short* Cb = (y == 0) ? Ck : (y == 1) ? Cv : Cr;

  // XCD-aware bijective swizzle within this y's 256 blocks
  const int nwg = (int)gridDim.x;
  const int q = nwg >> 3;
  const int wg = (blockIdx.x & 7) * q + (blockIdx.x >> 3);
  const int GM = M >> 8;
  const int bm = (wg % GM) * 256;
  const int bn = (wg / GM) * 256;

  const int wm = (wave >> 2) * 128;
  const int wn = (wave & 3) * 64;
  const int l15 = lane & 15;
  const int lg = lane >> 4;

  f32x4 acc[8][4] = {};

  // ---- tm preload (drained before pipeline; keeps vmcnt ledger exact) ----
  ((float4*)ltm)[tid] = ((const float4*)tm)[tid];   // 512 x 4 floats = 2048
  asm volatile("s_waitcnt vmcnt(0) lgkmcnt(0)" ::: "memory");
  __builtin_amdgcn_sched_barrier(0);

  // ---- A mix-staging setup: thread -> (row = tid>>1, k-half = tid&1) ----
  const int arow = tid >> 1;
  const int akh = (tid & 1) << 4;                 // 0 or 16 floats
  const int grow = bm + arow;
  const int s = grow & (S - 1);
  const float* hc = hidden + (long long)grow * K + akh;
  const float* hp = hc - (s > 0 ? K : 0);         // clamped; zeroed via psel
  const float psel = (s > 0) ? 1.f : 0.f;
  const int ac0 = (tid & 1) * 2;
  const int aw0 = arow * 32 + (((ac0 + 0) ^ ((arow >> 1) & 3)) << 3);
  const int aw1 = arow * 32 + (((ac0 + 1) ^ ((arow >> 1) & 3)) << 3);

  float4 hcur[2][4], hprv[2][4];                  // ping-pong in-flight rows

#define ISSUE_H(pp)                                                   \
  {                                                                   \
    _Pragma("unroll") for (int j = 0; j < 4; ++j)                     \
        hcur[pp][j] = *(const float4*)(hc + 4 * j);                   \
    _Pragma("unroll") for (int j = 0; j < 4; ++j)                     \
        hprv[pp][j] = *(const float4*)(hp + 4 * j);                   \
    hc += 32; hp += 32;                                               \
  }

#define EXF(v, c) ((c) == 0 ? (v).x : (c) == 1 ? (v).y : (c) == 2 ? (v).z : (v).w)

#define DO_MIX(pp, aslot, tp1)                                        \
  {                                                                   \
    unsigned short* ab = lds + (aslot) * 8192;                        \
    const float* lt = ltm + 32 * (tp1) + akh;                         \
    float4 tq[4];                                                     \
    _Pragma("unroll") for (int j = 0; j < 4; ++j)                     \
        tq[j] = *(const float4*)(lt + 4 * j);                         \
    unsigned short xs[16];                                            \
    _Pragma("unroll") for (int j = 0; j < 16; ++j) {                  \
      float c = EXF(hcur[pp][j >> 2], j & 3);                         \
      float p = EXF(hprv[pp][j >> 2], j & 3) * psel;                  \
      float mm = EXF(tq[j >> 2], j & 3);                              \
      xs[j] = f2bf(c * mm + p * (1.f - mm));                          \
    }                                                                 \
    *(s16x8*)(ab + aw0) = *(const s16x8*)&xs[0];                      \
    *(s16x8*)(ab + aw1) = *(const s16x8*)&xs[8];                      \
  }

  // ---- B staging (r5-verified inverse-swizzle gload pair) ----
  const int srow = tid >> 2;
  const int sg = ((tid & 3) ^ ((srow >> 1) & 3)) * 8;
  const unsigned short* gB0 = B + (long long)(bn + srow) * K + sg;
  const unsigned short* gB1 = B + (long long)(bn + 128 + srow) * K + sg;

#define STAGE_B(bsl)                                                  \
  {                                                                   \
    unsigned short* d = lds + 16384 + (bsl) * 8192 + wave * 512;      \
    gload_lds16(gB0, d);                                              \
    gload_lds16(gB1, d + 4096);                                       \
    gB0 += 32; gB1 += 32;                                             \
  }

  // ---- fragment offsets (within slot; r5-verified swizzle formula) ----
  int offA[8], offB[4];
#pragma unroll
  for (int mi = 0; mi < 8; ++mi) {
    int R = wm + mi * 16 + l15;
    offA[mi] = R * 32 + ((lg ^ ((R >> 1) & 3)) * 8);
  }
#pragma unroll
  for (int ni = 0; ni < 4; ++ni) {
    int R = wn + ni * 16 + l15;
    offB[ni] = R * 32 + ((lg ^ ((R >> 1) & 3)) * 8);
  }

  const int NT = K >> 5;   // 64 (even, >= 4)

  // ---- prologue ----
  ISSUE_H(0);            // tile 0 -> buf0      [8]
  ISSUE_H(1);            // tile 1 -> buf1      [8]
  STAGE_B(0);            // C(0)                [2]
  STAGE_B(1);            // C(1)                [2]
  asm volatile("s_waitcnt vmcnt(12)" ::: "memory");   // H(0) landed
  __builtin_amdgcn_sched_barrier(0);
  DO_MIX(0, 0, 0);       // W(0) -> A slot 0
  asm volatile("s_waitcnt vmcnt(2)" ::: "memory");    // C(0)+H(1) landed
  __builtin_amdgcn_sched_barrier(0);
  asm volatile("s_waitcnt lgkmcnt(0)" ::: "memory");  // W(0) drained
  __builtin_amdgcn_sched_barrier(0);
  __builtin_amdgcn_s_barrier();

#define K_ITER(T, PP)                                                         \
  {                                                                           \
    const int t_ = (T);                                                       \
    const unsigned short* aB = lds + ((t_) & 1) * 8192;                       \
    const unsigned short* bB = lds + 16384 + ((t_) % 3) * 8192;               \
    /* ---- P0: m-half 0 ---- */                                              \
    if (t_ + 2 < NT) {                                                        \
      ISSUE_H(PP);                                                            \
      asm volatile("s_waitcnt vmcnt(10)" ::: "memory");                       \
    } else if (t_ + 1 < NT) {                                                 \
      asm volatile("s_waitcnt vmcnt(2)" ::: "memory");                        \
    }                                                                         \
    __builtin_amdgcn_sched_barrier(0);                                        \
    if (t_ + 1 < NT) DO_MIX(PP ^ 1, (t_ + 1) & 1, t_ + 1);                    \
    s16x8 a0[4], b0[4];                                                       \
    _Pragma("unroll") for (int mi = 0; mi < 4; ++mi)                          \
        a0[mi] = *(const s16x8*)(aB + offA[mi]);                              \
    _Pragma("unroll") for (int ni = 0; ni < 4; ++ni)                          \
        b0[ni] = *(const s16x8*)(bB + offB[ni]);                              \
    __builtin_amdgcn_s_barrier();                                             \
    asm volatile("s_waitcnt lgkmcnt(0)" ::: "memory");                        \
    __builtin_amdgcn_sched_barrier(0);                                        \
    __builtin_amdgcn_s_setprio(1);                                            \
    _Pragma("unroll") for (int mi = 0; mi < 4; ++mi)                          \
        _Pragma("unroll") for (int ni = 0; ni < 4; ++ni)                      \
            acc[mi][ni] = __builtin_amdgcn_mfma_f32_16x16x32_bf16(            \
                a0[mi], b0[ni], acc[mi][ni], 0, 0, 0);                        \
    __builtin_amdgcn_s_setprio(0);                                            \
    __builtin_amdgcn_sched_barrier(0);                                        \
    __builtin_amdgcn_s_barrier();                                             \
    /* ---- P1: m-half 1 ---- */                                              \
    s16x8 a1[4];                                                              \
    _Pragma("unroll") for (int mi = 0; mi < 4; ++mi)                          \
        a1[mi] = *(const s16x8*)(aB + offA[4 + mi]);                          \
    if (t_ + 2 < NT) {                                                        \
      STAGE_B((t_ + 2) % 3);                                                  \
      asm volatile("s_waitcnt vmcnt(10)" ::: "memory");                       \
    } else if (t_ + 1 < NT) {                                                 \
      asm volatile("s_waitcnt vmcnt(0)" ::: "memory");                        \
    }                                                                         \
    __builtin_amdgcn_sched_barrier(0);                                        \
    __builtin_amdgcn_s_barrier();                                             \
    asm volatile("s_waitcnt lgkmcnt(0)" ::: "memory");                        \
    __builtin_amdgcn_sched_barrier(0);                                        \
    __builtin_amdgcn_s_setprio(1);                                            \
    _Pragma("unroll") for (int mi = 0; mi < 4; ++mi)                          \
        _Pragma("unroll") for (int ni = 0; ni < 4; ++ni)                      \
            acc[4 + mi][ni] = __builtin_amdgcn_mfma_f32_16x16x32_bf16(        \
                a1[mi], b0[ni], acc[4 + mi][ni], 0, 0, 0);                    \
    __builtin_amdgcn_s_setprio(0);                                            \
    __builtin_amdgcn_sched_barrier(0);                                        \
    __builtin_amdgcn_s_barrier();                                             \
  }

  for (int t = 0; t < NT; t += 2) {
    K_ITER(t, 0);
    K_ITER(t + 1, 1);
  }
#undef K_ITER
#undef STAGE_B
#undef DO_MIX
#undef ISSUE_H
#undef EXF

  // epilogue: 16x16 C/D col = lane&15, row = (lane>>4)*4 + reg
#pragma unroll
  for (int mi = 0; mi < 8; ++mi)
#pragma unroll
    for (int ni = 0; ni < 4; ++ni)
#pragma unroll
      for (int r = 0; r < 4; ++r) {
        int row = bm + wm + mi * 16 + lg * 4 + r;
        int col = bn + wn + ni * 16 + l15;
        float v = acc[mi][ni][r];
        if (y == 2) v = 1.f / (1.f + __expf(-v));
        Cb[(long long)row * N + col] = f2bf(v);
      }
}

// ---------------- bf16 NT GEMM (r5-verified, for the output projection) ----
// 256x256 tile, BK=32, ring-4 slots (128 KiB), stage-3-ahead vmcnt(8),
// m201-phase shape, 16x16x32 frags. EPI: 0 = fp32.

template <int EPI>
__global__ __launch_bounds__(512, 2) void gemm_bt(
    const unsigned short* __restrict__ A, const unsigned short* __restrict__ B,
    float* __restrict__ Cf, unsigned short* __restrict__ Cb,
    int M, int N, int K) {
  __shared__ unsigned short lds[4 * 16384];

  const int tid = threadIdx.x;
  const int wave = tid >> 6;
  const int lane = tid & 63;

  const int nwg = (int)gridDim.x;
  const int q = nwg >> 3;
  const int wg = (blockIdx.x & 7) * q + (blockIdx.x >> 3);
  const int GM = M >> 8;
  const int bm = (wg % GM) * 256;
  const int bn = (wg / GM) * 256;

  const int wm = (wave >> 2) * 128;
  const int wn = (wave & 3) * 64;
  const int l15 = lane & 15;
  const int lg = lane >> 4;

  f32x4 acc[8][4] = {};

  const int srow = tid >> 2;
  const int sg = ((tid & 3) ^ ((srow >> 1) & 3)) * 8;
  const unsigned short* gA0 = A + (long long)(bm + srow) * K + sg;
  const unsigned short* gA1 = A + (long long)(bm + 128 + srow) * K + sg;
  const unsigned short* gB0 = B + (long long)(bn + srow) * K + sg;
  const unsigned short* gB1 = B + (long long)(bn + 128 + srow) * K + sg;

#define STAGE_A(sl)                                            \
  {                                                            \
    unsigned short* dst = lds + (sl) * 16384 + wave * 512;     \
    gload_lds16(gA0, dst);                                     \
    gload_lds16(gA1, dst + 4096);                              \
    gA0 += 32; gA1 += 32;                                      \
  }
#define STAGE_B(sl)                                            \
  {                                                            \
    unsigned short* dst = lds + (sl) * 16384 + wave * 512;     \
    gload_lds16(gB0, dst + 8192);                              \
    gload_lds16(gB1, dst + 12288);                             \
    gB0 += 32; gB1 += 32;                                      \
  }

  int offA[8], offB[4];
#pragma unroll
  for (int mi = 0; mi < 8; ++mi) {
    int R = wm + mi * 16 + l15;
    offA[mi] = R * 32 + ((lg ^ ((R >> 1) & 3)) * 8);
  }
#pragma unroll
  for (int ni = 0; ni < 4; ++ni) {
    int R = wn + ni * 16 + l15;
    offB[ni] = 8192 + R * 32 + ((lg ^ ((R >> 1) & 3)) * 8);
  }

  const int NT = K >> 5;

  STAGE_A(0); STAGE_B(0);
  STAGE_A(1); STAGE_B(1);
  STAGE_A(2); STAGE_B(2);
  asm volatile("s_waitcnt vmcnt(8)" ::: "memory");
  __builtin_amdgcn_sched_barrier(0);
  __builtin_amdgcn_s_barrier();

  for (int t = 0; t < NT; ++t) {
    const unsigned short* sb = lds + (t & 3) * 16384;
    const bool pf = (t + 3 < NT);

    s16x8 a[4], b[4];
#pragma unroll
    for (int mi = 0; mi < 4; ++mi) a[mi] = *(const s16x8*)(sb + offA[mi]);
#pragma unroll
    for (int ni = 0; ni < 4; ++ni) b[ni] = *(const s16x8*)(sb + offB[ni]);
    if (pf) STAGE_A((t + 3) & 3);
    __builtin_amdgcn_sched_barrier(0);
    __builtin_amdgcn_s_barrier();
    asm volatile("s_waitcnt lgkmcnt(0)" ::: "memory");
    __builtin_amdgcn_sched_barrier(0);
    __builtin_amdgcn_s_setprio(1);
#pragma unroll
    for (int mi = 0; mi < 4; ++mi)
#pragma unroll
      for (int ni = 0; ni < 4; ++ni)
        acc[mi][ni] = __builtin_amdgcn_mfma_f32_16x16x32_bf16(
            a[mi], b[ni], acc[mi][ni], 0, 0, 0);
    __builtin_amdgcn_s_setprio(0);
    __builtin_amdgcn_sched_barrier(0);
    __builtin_amdgcn_s_barrier();

    s16x8 a2[4];
#pragma unroll
    for (int mi = 0; mi < 4; ++mi) a2[mi] = *(const s16x8*)(sb + offA[4 + mi]);
    if (pf) STAGE_B((t + 3) & 3);
    if (pf) {
      asm volatile("s_waitcnt vmcnt(8)" ::: "memory");
    } else if (t + 3 == NT) {
      asm volatile("s_waitcnt vmcnt(4)" ::: "memory");
    } else if (t + 2 == NT) {
      asm volatile("s_waitcnt vmcnt(0)" ::: "memory");
    }
    __builtin_amdgcn_sched_barrier(0);
    __builtin_amdgcn_s_barrier();
    asm volatile("s_waitcnt lgkmcnt(0)" ::: "memory");
    __builtin_amdgcn_sched_barrier(0);
    __builtin_amdgcn_s_setprio(1);
#pragma unroll
    for (int mi = 0; mi < 4; ++mi)
#pragma unroll
      for (int ni = 0; ni < 4; ++ni)
        acc[4 + mi][ni] = __builtin_amdgcn_mfma_f32_16x16x32_bf16(
            a2[mi], b[ni], acc[4 + mi][ni], 0, 0, 0);
    __builtin_amdgcn_s_setprio(0);
    __builtin_amdgcn_sched_barrier(0);
    __builtin_amdgcn_s_barrier();
  }
#undef STAGE_A
#undef STAGE_B

#pragma unroll
  for (int mi = 0; mi < 8; ++mi)
#pragma unroll
    for (int ni = 0; ni < 4; ++ni)
#pragma unroll
      for (int r = 0; r < 4; ++r) {
        int row = bm + wm + mi * 16 + lg * 4 + r;
        int col = bn + wn + ni * 16 + l15;
        float v = acc[mi][ni][r];
        long long idx = (long long)row * N + col;
        if (EPI == 0) {
          Cf[idx] = v;
        } else if (EPI == 1) {
          float s = 1.f / (1.f + __expf(-v));
          Cb[idx] = f2bf(s);
        } else {
          Cb[idx] = f2bf(v);
        }
      }
}

// ---------------- chunked WKV scan (bf16 k/v/r), scalar form ----------------

#define NEG_INF_F (-1e38f)

__global__ void scan_phase1(const unsigned short* __restrict__ kb,
                            const unsigned short* __restrict__ vb,
                            const float* __restrict__ td,
                            float* __restrict__ locN, float* __restrict__ locD,
                            float* __restrict__ locM,
                            int S, int D, int C, int L) {
  int t = blockIdx.x * blockDim.x + threadIdx.x;
  int d = t % D;
  int c = (t / D) % C;
  int b = t / (D * C);
  float w = -__expf(td[d]);
  float num = 0.f, den = 0.f, m = NEG_INF_F;
  long long base = ((long long)(b * S + c * L)) * D + d;
  for (int i = 0; i < L; ++i) {
    float kk = bf2f(kb[base]);
    float vv = bf2f(vb[base]);
    base += D;
    float mn = fmaxf(m + w, kk);
    float e1 = __expf(m + w - mn);
    float e2 = __expf(kk - mn);
    num = e1 * num + e2 * vv;
    den = e1 * den + e2;
    m = mn;
  }
  int o = (b * C + c) * D + d;
  locN[o] = num; locD[o] = den; locM[o] = m;
}

__global__ void scan_phase2(const float* __restrict__ td,
                            const float* __restrict__ locN, const float* __restrict__ locD,
                            const float* __restrict__ locM,
                            float* __restrict__ inN, float* __restrict__ inD,
                            float* __restrict__ inM,
                            int Bc, int D, int C, int L) {
  int t = blockIdx.x * blockDim.x + threadIdx.x;
  if (t >= Bc * D) return;
  int d = t % D, b = t / D;
  float w = -__expf(td[d]);
  float Lw = (float)L * w;
  float num = 0.f, den = 0.f, m = NEG_INF_F;
  for (int c = 0; c < C; ++c) {
    int o = (b * C + c) * D + d;
    inN[o] = num; inD[o] = den; inM[o] = m;
    float sm = m + Lw;
    float lm = locM[o];
    float m2 = fmaxf(sm, lm);
    float e1 = __expf(sm - m2);
    float e2 = __expf(lm - m2);
    num = e1 * num + e2 * locN[o];
    den = e1 * den + e2 * locD[o];
    m = m2;
  }
}

__global__ void scan_phase3(const unsigned short* __restrict__ kb,
                            const unsigned short* __restrict__ vb,
                            const unsigned short* __restrict__ rb,
                            const float* __restrict__ td, const float* __restrict__ tfirst,
                            const float* __restrict__ inN, const float* __restrict__ inD,
                            const float* __restrict__ inM,
                            unsigned short* __restrict__ rr,
                            int S, int D, int C, int L) {
  int t = blockIdx.x * blockDim.x + threadIdx.x;
  int d = t % D;
  int c = (t / D) % C;
  int b = t / (D * C);
  float w = -__expf(td[d]);
  float tfd = tfirst[d];
  int o = (b * C + c) * D + d;
  float num = inN[o], den = inD[o], m = inM[o];
  long long base = ((long long)(b * S + c * L)) * D + d;
  for (int i = 0; i < L; ++i) {
    float kk = bf2f(kb[base]);
    float vv = bf2f(vb[base]);
    float rv = bf2f(rb[base]);
    float ktf = kk + tfd;
    float mo = fmaxf(m, ktf);
    float e1 = __expf(m - mo);
    float e2 = __expf(ktf - mo);
    float out = (e1 * num + e2 * vv) / (e1 * den + e2);
    rr[base] = f2bf(out * rv);
    float mn = fmaxf(m + w, kk);
    e1 = __expf(m + w - mn);
    e2 = __expf(kk - mn);
    num = e1 * num + e2 * vv;
    den = e1 * den + e2;
    m = mn;
    base += D;
  }
}

// ---------------- launch ----------------
// 6 dispatches. Workspace (<=110 MiB):
//   ws:    Wb4 [0,32) | states [32,38) | rb [38,70) | rr [70,102)
//   d_out: kb [0,32) | vb [32,64) | final fp32 [0,64)
// Disjointness:
//   conv4:    d_in weights -> Wb4.
//   gemm_kvr: reads hidden (d_in) + Wb + tm; writes kb, vb (d_out), rb (ws).
//             No xk/xv/xr buffers exist (mix fused into A-staging).
//   scans:    read kb, vb, rb -> states -> rr (ws).
//   gemm_o:   reads rr + Wb[3]; writes d_out fp32 (kb/vb dead after scan3).

extern "C" void kernel_launch(void* const* d_in, const int* in_sizes, int n_in,
                              void* d_out, int out_size, void* d_ws, size_t ws_size,
                              hipStream_t stream) {
  const float* hidden = (const float*)d_in[0];
  const float* td  = (const float*)d_in[1];
  const float* tfi = (const float*)d_in[2];
  const float* tmk = (const float*)d_in[3];
  const float* tmv = (const float*)d_in[4];
  const float* tmr = (const float*)d_in[5];
  const float* Wk  = (const float*)d_in[6];
  const float* Wv  = (const float*)d_in[7];
  const float* Wr  = (const float*)d_in[8];
  const float* Wo  = (const float*)d_in[9];
  float* out = (float*)d_out;

  const int H = in_sizes[1];                 // 2048
  const int D = H;
  const long long BS = (long long)in_sizes[0] / H;  // 8192
  const int S = 2048;
  const int B = (int)(BS / S);               // 4
  const int C = 32, L = S / C;

  char* ws = (char*)d_ws;
  const size_t MB = 1u << 20;
  unsigned short* Wb  = (unsigned short*)(ws + 0 * MB);
  float* locN         = (float*)(ws + 32 * MB);
  float* locD         = (float*)(ws + 33 * MB);
  float* locM         = (float*)(ws + 34 * MB);
  float* inN          = (float*)(ws + 35 * MB);
  float* inD          = (float*)(ws + 36 * MB);
  float* inM          = (float*)(ws + 37 * MB);
  unsigned short* rb  = (unsigned short*)(ws + 38 * MB);
  unsigned short* rr  = (unsigned short*)(ws + 70 * MB);

  unsigned short* kb  = (unsigned short*)d_out;
  unsigned short* vb  = (unsigned short*)((char*)d_out + 32 * MB);

  const long long HH = (long long)H * H;
  int n4w = H * H / 4;
  int cbk = (n4w + 255) / 256;
  int nwg = (int)((BS / 256) * (D / 256));   // 32 * 8 = 256

  // all 4 weight conversions, one dispatch
  conv_bf16_4<<<dim3(cbk, 4), 256, 0, stream>>>(
      (const float4*)Wk, (const float4*)Wv, (const float4*)Wr, (const float4*)Wo,
      (ushort4*)Wb, n4w);

  // fused mix + {k,v,r} GEMMs in one dispatch (768 blocks)
  gemm_kvr<<<dim3(nwg, 3), 512, 0, stream>>>(
      hidden, Wb, tmk, tmv, tmr, kb, vb, rb, (int)BS, D, H, S);

  // chunked WKV scan, fused r * rwkv -> rr (bf16)
  int nscan = B * C * D;
  scan_phase1<<<nscan / 256, 256, 0, stream>>>(kb, vb, td, locN, locD, locM, S, D, C, L);
  scan_phase2<<<(B * D + 255) / 256, 256, 0, stream>>>(td, locN, locD, locM, inN, inD, inM, B, D, C, L);
  scan_phase3<<<nscan / 256, 256, 0, stream>>>(kb, vb, rb, td, tfi, inN, inD, inM, rr, S, D, C, L);

  // out = (r * rwkv) @ Wo^T  (fp32 -> d_out; kb/vb dead now)
  gemm_bt<0><<<nwg, 512, 0, stream>>>(rr, Wb + 3 * HH, out, nullptr, (int)BS, H, D);
}